// Round 1
// baseline (456.403 us; speedup 1.0000x reference)
//
#include <hip/hip_runtime.h>
#include <hip/hip_bf16.h>
#include <math.h>

// Problem constants: B=4, L=2048, D=1024, H=16, hd=64
// M = B*L = 8192, QKV N = 3072, proj N = 1024, K = 1024

typedef unsigned short u16;
typedef __attribute__((ext_vector_type(8))) short bf8;   // 8 bf16 = 4 VGPR (MFMA A/B frag)
typedef __attribute__((ext_vector_type(4))) float f4;    // MFMA C/D frag

__device__ __forceinline__ u16 f2bf(float f) {
  unsigned int u = __float_as_uint(f);
  unsigned int r = (u + 0x7fffu + ((u >> 16) & 1u)) >> 16;
  return (u16)r;
}

__device__ __forceinline__ f4 mfma16(bf8 a, bf8 b, f4 c) {
  return __builtin_amdgcn_mfma_f32_16x16x32_bf16(a, b, c, 0, 0, 0);
}

__device__ __forceinline__ void async_copy16(const void* gsrc, void* ldst) {
  __builtin_amdgcn_global_load_lds(
      (__attribute__((address_space(1))) void*)gsrc,
      (__attribute__((address_space(3))) void*)ldst,
      16, 0, 0);
}

// ---------------- prep kernels ----------------

__global__ __launch_bounds__(256) void convert_bf16_k(const float* __restrict__ in,
                                                      u16* __restrict__ out, int n4) {
  int i = blockIdx.x * blockDim.x + threadIdx.x;
  if (i < n4) {
    float4 v = ((const float4*)in)[i];
    ushort4 o;
    o.x = f2bf(v.x); o.y = f2bf(v.y); o.z = f2bf(v.z); o.w = f2bf(v.w);
    ((ushort4*)out)[i] = o;
  }
}

// in [K][N] f32 row-major -> out [N][K] bf16 row-major (B^T layout). 64x64 tiles.
__global__ __launch_bounds__(256) void transpose_bf16_k(const float* __restrict__ in,
                                                        u16* __restrict__ out, int K, int N) {
  __shared__ float t[64][65];
  int k0 = blockIdx.x * 64;
  int n0 = blockIdx.y * 64;
  int tx = threadIdx.x & 63, ty = threadIdx.x >> 6;  // 4 rows per pass
  for (int i = 0; i < 16; i++) {
    int r = ty + i * 4;
    t[r][tx] = in[(size_t)(k0 + r) * N + n0 + tx];
  }
  __syncthreads();
  for (int i = 0; i < 16; i++) {
    int r = ty + i * 4;
    out[(size_t)(n0 + r) * K + k0 + tx] = f2bf(t[tx][r]);
  }
}

// cos/sin tables [2048][32] f32
__global__ __launch_bounds__(256) void rope_tables_k(float* __restrict__ cosT,
                                                     float* __restrict__ sinT) {
  int i = blockIdx.x * blockDim.x + threadIdx.x;  // 65536
  int l = i >> 5, j = i & 31;
  float inv = powf(10000.0f, -(float)j / 32.0f);
  float f = (float)l * inv;
  cosT[i] = cosf(f);
  sinT[i] = sinf(f);
}

// ---------------- GEMM (A[M][K]bf16 x Bt[N][K]bf16) ----------------
// 128x128 tile, BK=64, 4 waves (2x2), each wave 64x64 (4x4 frags of 16x16x32).
// LDS tiles are [128 rows][128 bytes] with XOR swizzle byte ^= ((row&7)<<4),
// applied on the global SOURCE address (global_load_lds writes linearly) and on reads.
// EPI==0: out f32 += bias. EPI==1: fused bias+RoPE epilogue -> Qb/Kb [bh][l][64], Vt [bh][64][l].

template <int EPI>
__global__ __launch_bounds__(256, 2) void gemm_bt(
    const u16* __restrict__ A, const u16* __restrict__ Bt, const float* __restrict__ bias,
    float* __restrict__ outF,
    u16* __restrict__ Qb, u16* __restrict__ Kb, u16* __restrict__ Vt,
    const float* __restrict__ cosT, const float* __restrict__ sinT,
    int M, int N, int K) {
  __shared__ __attribute__((aligned(16))) u16 lA[128 * 64];
  __shared__ __attribute__((aligned(16))) u16 lB[128 * 64];
  const int tid = threadIdx.x;
  const int lane = tid & 63, wid = tid >> 6;
  const int nTilesN = N >> 7;
  const int bm = blockIdx.x / nTilesN, bn = blockIdx.x % nTilesN;
  const int m0 = bm << 7, n0 = bn << 7;
  const int wm = (wid >> 1) << 6, wn = (wid & 1) << 6;
  const int g = lane >> 4, c0 = lane & 15;

  f4 acc[4][4];
  for (int i = 0; i < 4; i++)
    for (int j = 0; j < 4; j++) acc[i][j] = (f4)0.0f;

  for (int k0 = 0; k0 < K; k0 += 64) {
    __syncthreads();
    for (int i = 0; i < 4; i++) {
      int chunk = i * 4 + wid;
      int p = chunk * 1024 + lane * 16;
      int row = p >> 7, pb = p & 127;
      int lb = pb ^ ((row & 7) << 4);
      async_copy16((const char*)(A + (size_t)(m0 + row) * K + k0) + lb,
                   (char*)lA + chunk * 1024);
    }
    for (int i = 0; i < 4; i++) {
      int chunk = i * 4 + wid;
      int p = chunk * 1024 + lane * 16;
      int row = p >> 7, pb = p & 127;
      int lb = pb ^ ((row & 7) << 4);
      async_copy16((const char*)(Bt + (size_t)(n0 + row) * K + k0) + lb,
                   (char*)lB + chunk * 1024);
    }
    __syncthreads();
    bf8 a[4][2], b[4][2];
    for (int ks = 0; ks < 2; ks++) {
      int cb = ks * 64 + g * 16;
      for (int mf = 0; mf < 4; mf++) {
        int row = wm + mf * 16 + c0;
        a[mf][ks] = *(const bf8*)((const char*)lA + (row << 7) + (cb ^ ((row & 7) << 4)));
      }
      for (int nf = 0; nf < 4; nf++) {
        int row = wn + nf * 16 + c0;
        b[nf][ks] = *(const bf8*)((const char*)lB + (row << 7) + (cb ^ ((row & 7) << 4)));
      }
    }
    for (int ks = 0; ks < 2; ks++)
      for (int mf = 0; mf < 4; mf++)
        for (int nf = 0; nf < 4; nf++)
          acc[mf][nf] = mfma16(a[mf][ks], b[nf][ks], acc[mf][nf]);
  }

  // C frag mapping (verified m89/m91): col = c0 + 16*nf (+wn+n0), row = 4*g + reg (+16*mf+wm+m0)
  if (EPI == 0) {
    for (int nf = 0; nf < 4; nf++) {
      int col = n0 + wn + nf * 16 + c0;
      float bv = bias[col];
      for (int mf = 0; mf < 4; mf++) {
        int rowb = m0 + wm + mf * 16 + g * 4;
        for (int r = 0; r < 4; r++)
          outF[(size_t)(rowb + r) * N + col] = acc[mf][nf][r] + bv;
      }
    }
  } else {
    for (int nf = 0; nf < 4; nf++) {
      int col = n0 + wn + nf * 16 + c0;
      int sec = col >> 10;          // 0=q 1=k 2=v
      int hc = col & 1023;
      int h = hc >> 6, d = hc & 63;
      float bv = bias[col];
      int pcol = n0 + wn + (nf ^ 2) * 16 + c0;  // RoPE partner col (d +/- 32), same lane
      float pbv = bias[pcol];
      for (int mf = 0; mf < 4; mf++) {
        int rowb = m0 + wm + mf * 16 + g * 4;
        for (int r = 0; r < 4; r++) {
          int row = rowb + r;
          int bb = row >> 11, l = row & 2047;
          int bh = bb * 16 + h;
          float v = acc[mf][nf][r] + bv;
          if (sec == 2) {
            Vt[((size_t)bh * 64 + d) * 2048 + l] = f2bf(v);  // V stored transposed [bh][d][l]
          } else {
            int dm = d & 31;
            float cz = cosT[l * 32 + dm], sz = sinT[l * 32 + dm];
            float pv = acc[mf][nf ^ 2][r] + pbv;
            float o = (d < 32) ? (v * cz - pv * sz) : (v * cz + pv * sz);
            u16* dst = (sec == 0) ? Qb : Kb;
            dst[((size_t)bh * 2048 + l) * 64 + d] = f2bf(o);
          }
        }
      }
    }
  }
}

// ---------------- flash attention ----------------
// grid (L/128, B*H); block 256 = 4 waves, each wave owns 32 q-rows.
// K tile [64 kv][64 d] and V^T tile [64 d][64 kv] staged via global_load_lds (XOR swizzled).
// Online softmax per q-row via 16-lane shfl_xor reductions. P transposed through padded LDS.
__global__ __launch_bounds__(256, 2) void attn_fwd(
    const u16* __restrict__ Qb, const u16* __restrict__ Kb, const u16* __restrict__ Vt,
    u16* __restrict__ attnOut) {
  __shared__ __attribute__((aligned(16))) u16 kT[64 * 64];
  __shared__ __attribute__((aligned(16))) u16 vT[64 * 64];
  __shared__ __attribute__((aligned(16))) u16 pT[4][32 * 72];  // per-wave, stride 72 (pad)
  const int tid = threadIdx.x, lane = tid & 63, wid = tid >> 6;
  const int bh = blockIdx.y;
  const int q0 = blockIdx.x * 128;
  const int bb = bh >> 4, h = bh & 15;
  const u16* Qp = Qb + (size_t)bh * 2048 * 64;
  const u16* Kp = Kb + (size_t)bh * 2048 * 64;
  const u16* Vp = Vt + (size_t)bh * 64 * 2048;  // [64 d][2048 l]
  const int g = lane >> 4, c0 = lane & 15;
  const int qw = q0 + wid * 32;

  // Q frags hoisted (A-operand: row=c0, k contiguous)
  bf8 aq[2][2];
  for (int mf = 0; mf < 2; mf++)
    for (int ks = 0; ks < 2; ks++) {
      int row = qw + mf * 16 + c0;
      aq[mf][ks] = *(const bf8*)((const char*)(Qp + (size_t)row * 64) + ks * 64 + g * 16);
    }

  f4 accO[2][4];
  for (int i = 0; i < 2; i++)
    for (int j = 0; j < 4; j++) accO[i][j] = (f4)0.0f;
  float mrun[2][4], lrun[2][4];
  for (int mf = 0; mf < 2; mf++)
    for (int r = 0; r < 4; r++) { mrun[mf][r] = -INFINITY; lrun[mf][r] = 0.f; }

  const int nkt = (q0 >> 6) + 2;  // causal: kv tiles up to q-block end
  for (int kt = 0; kt < nkt; kt++) {
    int kv0 = kt * 64;
    __syncthreads();
    for (int i = 0; i < 2; i++) {
      int chunk = i * 4 + wid;
      int p = chunk * 1024 + lane * 16;
      int row = p >> 7, pb = p & 127;
      int lb = pb ^ ((row & 7) << 4);
      async_copy16((const char*)(Kp + (size_t)(kv0 + row) * 64) + lb, (char*)kT + chunk * 1024);
      async_copy16((const char*)(Vp + (size_t)row * 2048 + kv0) + lb, (char*)vT + chunk * 1024);
    }
    __syncthreads();

    // S = Q K^T
    f4 s[2][4];
    for (int i = 0; i < 2; i++)
      for (int j = 0; j < 4; j++) s[i][j] = (f4)0.0f;
    bf8 bk[4][2];
    for (int ks = 0; ks < 2; ks++) {
      int cb = ks * 64 + g * 16;
      for (int nf = 0; nf < 4; nf++) {
        int row = nf * 16 + c0;
        bk[nf][ks] = *(const bf8*)((const char*)kT + (row << 7) + (cb ^ ((row & 7) << 4)));
      }
    }
    for (int ks = 0; ks < 2; ks++)
      for (int mf = 0; mf < 2; mf++)
        for (int nf = 0; nf < 4; nf++)
          s[mf][nf] = mfma16(aq[mf][ks], bk[nf][ks], s[mf][nf]);

    // scale + causal mask
    for (int mf = 0; mf < 2; mf++)
      for (int nf = 0; nf < 4; nf++) {
        int kvg = kv0 + nf * 16 + c0;
        for (int r = 0; r < 4; r++) {
          int qg = qw + mf * 16 + g * 4 + r;
          float v = s[mf][nf][r] * 0.125f;
          s[mf][nf][r] = (kvg > qg) ? -INFINITY : v;
        }
      }

    // online softmax (rows owned by 16-lane groups)
    float pcorr[2][4], mnew[2][4];
    for (int mf = 0; mf < 2; mf++)
      for (int r = 0; r < 4; r++) {
        float mx = fmaxf(fmaxf(s[mf][0][r], s[mf][1][r]), fmaxf(s[mf][2][r], s[mf][3][r]));
        for (int off = 1; off < 16; off <<= 1) mx = fmaxf(mx, __shfl_xor(mx, off));
        float mn = fmaxf(mrun[mf][r], mx);
        mnew[mf][r] = mn;
        pcorr[mf][r] = expf(mrun[mf][r] - mn);
      }
    for (int mf = 0; mf < 2; mf++)
      for (int r = 0; r < 4; r++) {
        float rs = 0.f;
        for (int nf = 0; nf < 4; nf++) {
          float p = expf(s[mf][nf][r] - mnew[mf][r]);
          s[mf][nf][r] = p;
          rs += p;
        }
        for (int off = 1; off < 16; off <<= 1) rs += __shfl_xor(rs, off);
        lrun[mf][r] = lrun[mf][r] * pcorr[mf][r] + rs;
        mrun[mf][r] = mnew[mf][r];
      }

    // P -> per-wave LDS (transpose to A-operand layout)
    u16* pw = &pT[wid][0];
    for (int mf = 0; mf < 2; mf++)
      for (int nf = 0; nf < 4; nf++)
        for (int r = 0; r < 4; r++)
          pw[(mf * 16 + g * 4 + r) * 72 + nf * 16 + c0] = f2bf(s[mf][nf][r]);

    // rescale O
    for (int mf = 0; mf < 2; mf++)
      for (int nf = 0; nf < 4; nf++)
        for (int r = 0; r < 4; r++) accO[mf][nf][r] *= pcorr[mf][r];

    // O += P V
    bf8 pa[2][2], bv[4][2];
    for (int ksp = 0; ksp < 2; ksp++) {
      int cb = ksp * 64 + g * 16;
      for (int mf = 0; mf < 2; mf++) {
        int row = mf * 16 + c0;
        pa[mf][ksp] = *(const bf8*)((const char*)pw + row * 144 + cb);
      }
      for (int nf = 0; nf < 4; nf++) {
        int row = nf * 16 + c0;
        bv[nf][ksp] = *(const bf8*)((const char*)vT + (row << 7) + (cb ^ ((row & 7) << 4)));
      }
    }
    for (int ksp = 0; ksp < 2; ksp++)
      for (int mf = 0; mf < 2; mf++)
        for (int nf = 0; nf < 4; nf++)
          accO[mf][nf] = mfma16(pa[mf][ksp], bv[nf][ksp], accO[mf][nf]);
  }

  // finalize: attnOut [B*L][1024] bf16, row = b*2048+q, col = h*64+d
  for (int mf = 0; mf < 2; mf++)
    for (int r = 0; r < 4; r++) {
      int qg = qw + mf * 16 + g * 4 + r;
      float inv = 1.0f / lrun[mf][r];
      for (int nf = 0; nf < 4; nf++) {
        int d = nf * 16 + c0;
        attnOut[(size_t)(bb * 2048 + qg) * 1024 + h * 64 + d] = f2bf(accO[mf][nf][r] * inv);
      }
    }
}

// ---------------- launch ----------------

extern "C" void kernel_launch(void* const* d_in, const int* in_sizes, int n_in,
                              void* d_out, int out_size, void* d_ws, size_t ws_size,
                              hipStream_t stream) {
  const float* x      = (const float*)d_in[0];
  const float* qkv_w  = (const float*)d_in[1];
  const float* qkv_b  = (const float*)d_in[2];
  const float* proj_w = (const float*)d_in[3];
  const float* proj_b = (const float*)d_in[4];
  float* out = (float*)d_out;

  char* ws = (char*)d_ws;
  u16* xb      = (u16*)ws;  ws += (size_t)8192 * 1024 * 2;
  u16* wqkvT   = (u16*)ws;  ws += (size_t)3072 * 1024 * 2;
  u16* wprojT  = (u16*)ws;  ws += (size_t)1024 * 1024 * 2;
  float* cosT  = (float*)ws; ws += (size_t)2048 * 32 * 4;
  float* sinT  = (float*)ws; ws += (size_t)2048 * 32 * 4;
  u16* Qb      = (u16*)ws;  ws += (size_t)64 * 2048 * 64 * 2;
  u16* Kb      = (u16*)ws;  ws += (size_t)64 * 2048 * 64 * 2;
  u16* Vt      = (u16*)ws;  ws += (size_t)64 * 2048 * 64 * 2;
  u16* attnOut = (u16*)ws;  ws += (size_t)8192 * 1024 * 2;
  // total ws usage ~92.3 MB

  convert_bf16_k<<<8192, 256, 0, stream>>>(x, xb, 8192 * 1024 / 4);
  {
    dim3 tg(16, 48);
    transpose_bf16_k<<<tg, 256, 0, stream>>>(qkv_w, wqkvT, 1024, 3072);
  }
  {
    dim3 tg(16, 16);
    transpose_bf16_k<<<tg, 256, 0, stream>>>(proj_w, wprojT, 1024, 1024);
  }
  rope_tables_k<<<256, 256, 0, stream>>>(cosT, sinT);

  gemm_bt<1><<<64 * 24, 256, 0, stream>>>(xb, wqkvT, qkv_b, nullptr,
                                          Qb, Kb, Vt, cosT, sinT, 8192, 3072, 1024);
  {
    dim3 ag(16, 64);
    attn_fwd<<<ag, 256, 0, stream>>>(Qb, Kb, Vt, attnOut);
  }
  gemm_bt<0><<<64 * 8, 256, 0, stream>>>(attnOut, wprojT, proj_b, out,
                                         nullptr, nullptr, nullptr, nullptr, nullptr,
                                         8192, 1024, 1024);
}

// Round 2
// 235.182 us; speedup vs baseline: 1.9406x; 1.9406x over previous
//
#include <hip/hip_runtime.h>
#include <hip/hip_bf16.h>
#include <math.h>

// Problem constants: B=4, L=2048, D=1024, H=16, hd=64
// M = B*L = 8192, QKV N = 3072, proj N = 1024, K = 1024

typedef unsigned short u16;
typedef __attribute__((ext_vector_type(8))) short bf8;   // 8 bf16 = 4 VGPR (MFMA A/B frag, K=32)
typedef __attribute__((ext_vector_type(4))) short bf4;   // 4 bf16 = 2 VGPR (MFMA A/B frag, K=16)
typedef __attribute__((ext_vector_type(4))) float f4;    // MFMA C/D frag

__device__ __forceinline__ u16 f2bf(float f) {
  unsigned int u = __float_as_uint(f);
  unsigned int r = (u + 0x7fffu + ((u >> 16) & 1u)) >> 16;
  return (u16)r;
}

__device__ __forceinline__ f4 mfma16(bf8 a, bf8 b, f4 c) {
  return __builtin_amdgcn_mfma_f32_16x16x32_bf16(a, b, c, 0, 0, 0);
}

__device__ __forceinline__ f4 mfma16x16(bf4 a, bf4 b, f4 c) {
#if __has_builtin(__builtin_amdgcn_mfma_f32_16x16x16bf16_1k)
  return __builtin_amdgcn_mfma_f32_16x16x16bf16_1k(a, b, c, 0, 0, 0);
#elif __has_builtin(__builtin_amdgcn_mfma_f32_16x16x16_bf16)
  return __builtin_amdgcn_mfma_f32_16x16x16_bf16(a, b, c, 0, 0, 0);
#else
  f4 d;
  asm volatile("v_mfma_f32_16x16x16_bf16 %0, %1, %2, %3"
               : "=v"(d) : "v"(a), "v"(b), "v"(c));
  return d;
#endif
}

__device__ __forceinline__ float fexp2(float x) {
#if __has_builtin(__builtin_amdgcn_exp2f)
  return __builtin_amdgcn_exp2f(x);
#else
  return exp2f(x);
#endif
}

__device__ __forceinline__ void async_copy16(const void* gsrc, void* ldst) {
  __builtin_amdgcn_global_load_lds(
      (__attribute__((address_space(1))) void*)gsrc,
      (__attribute__((address_space(3))) void*)ldst,
      16, 0, 0);
}

// ---------------- prep kernels ----------------

__global__ __launch_bounds__(256) void convert_bf16_k(const float* __restrict__ in,
                                                      u16* __restrict__ out, int n4) {
  int i = blockIdx.x * blockDim.x + threadIdx.x;
  if (i < n4) {
    float4 v = ((const float4*)in)[i];
    ushort4 o;
    o.x = f2bf(v.x); o.y = f2bf(v.y); o.z = f2bf(v.z); o.w = f2bf(v.w);
    ((ushort4*)out)[i] = o;
  }
}

// in [K][N] f32 row-major -> out [N][K] bf16 row-major (B^T layout). 64x64 tiles.
__global__ __launch_bounds__(256) void transpose_bf16_k(const float* __restrict__ in,
                                                        u16* __restrict__ out, int K, int N) {
  __shared__ float t[64][65];
  int k0 = blockIdx.x * 64;
  int n0 = blockIdx.y * 64;
  int tx = threadIdx.x & 63, ty = threadIdx.x >> 6;  // 4 rows per pass
  for (int i = 0; i < 16; i++) {
    int r = ty + i * 4;
    t[r][tx] = in[(size_t)(k0 + r) * N + n0 + tx];
  }
  __syncthreads();
  for (int i = 0; i < 16; i++) {
    int r = ty + i * 4;
    out[(size_t)(n0 + r) * K + k0 + tx] = f2bf(t[tx][r]);
  }
}

// cos/sin tables [2048][32] f32
__global__ __launch_bounds__(256) void rope_tables_k(float* __restrict__ cosT,
                                                     float* __restrict__ sinT) {
  int i = blockIdx.x * blockDim.x + threadIdx.x;  // 65536
  int l = i >> 5, j = i & 31;
  float inv = powf(10000.0f, -(float)j / 32.0f);
  float f = (float)l * inv;
  cosT[i] = cosf(f);
  sinT[i] = sinf(f);
}

// ---------------- GEMM (A[M][K]bf16 x Bt[N][K]bf16) ----------------
// 128x128 tile, BK=64, 4 waves (2x2), each wave 64x64 (4x4 frags of 16x16x32).
// LDS tiles are [128 rows][128 bytes] with XOR swizzle byte ^= ((row&7)<<4),
// applied on the global SOURCE address (global_load_lds writes linearly) and on reads.
// EPI==0: out f32 += bias. EPI==1: fused bias+RoPE epilogue -> Qb/Kb [bh][l][64], Vt [bh][64][l].

template <int EPI>
__global__ __launch_bounds__(256, 2) void gemm_bt(
    const u16* __restrict__ A, const u16* __restrict__ Bt, const float* __restrict__ bias,
    float* __restrict__ outF,
    u16* __restrict__ Qb, u16* __restrict__ Kb, u16* __restrict__ Vt,
    const float* __restrict__ cosT, const float* __restrict__ sinT,
    int M, int N, int K) {
  __shared__ __attribute__((aligned(16))) u16 lA[128 * 64];
  __shared__ __attribute__((aligned(16))) u16 lB[128 * 64];
  const int tid = threadIdx.x;
  const int lane = tid & 63, wid = tid >> 6;
  const int nTilesN = N >> 7;
  const int bm = blockIdx.x / nTilesN, bn = blockIdx.x % nTilesN;
  const int m0 = bm << 7, n0 = bn << 7;
  const int wm = (wid >> 1) << 6, wn = (wid & 1) << 6;
  const int g = lane >> 4, c0 = lane & 15;

  f4 acc[4][4];
  for (int i = 0; i < 4; i++)
    for (int j = 0; j < 4; j++) acc[i][j] = (f4)0.0f;

  for (int k0 = 0; k0 < K; k0 += 64) {
    __syncthreads();
    for (int i = 0; i < 4; i++) {
      int chunk = i * 4 + wid;
      int p = chunk * 1024 + lane * 16;
      int row = p >> 7, pb = p & 127;
      int lb = pb ^ ((row & 7) << 4);
      async_copy16((const char*)(A + (size_t)(m0 + row) * K + k0) + lb,
                   (char*)lA + chunk * 1024);
    }
    for (int i = 0; i < 4; i++) {
      int chunk = i * 4 + wid;
      int p = chunk * 1024 + lane * 16;
      int row = p >> 7, pb = p & 127;
      int lb = pb ^ ((row & 7) << 4);
      async_copy16((const char*)(Bt + (size_t)(n0 + row) * K + k0) + lb,
                   (char*)lB + chunk * 1024);
    }
    __syncthreads();
    bf8 a[4][2], b[4][2];
    for (int ks = 0; ks < 2; ks++) {
      int cb = ks * 64 + g * 16;
      for (int mf = 0; mf < 4; mf++) {
        int row = wm + mf * 16 + c0;
        a[mf][ks] = *(const bf8*)((const char*)lA + (row << 7) + (cb ^ ((row & 7) << 4)));
      }
      for (int nf = 0; nf < 4; nf++) {
        int row = wn + nf * 16 + c0;
        b[nf][ks] = *(const bf8*)((const char*)lB + (row << 7) + (cb ^ ((row & 7) << 4)));
      }
    }
    for (int ks = 0; ks < 2; ks++)
      for (int mf = 0; mf < 4; mf++)
        for (int nf = 0; nf < 4; nf++)
          acc[mf][nf] = mfma16(a[mf][ks], b[nf][ks], acc[mf][nf]);
  }

  // C frag mapping (verified m89/m91): col = c0 + 16*nf (+wn+n0), row = 4*g + reg (+16*mf+wm+m0)
  if (EPI == 0) {
    for (int nf = 0; nf < 4; nf++) {
      int col = n0 + wn + nf * 16 + c0;
      float bv = bias[col];
      for (int mf = 0; mf < 4; mf++) {
        int rowb = m0 + wm + mf * 16 + g * 4;
        for (int r = 0; r < 4; r++)
          outF[(size_t)(rowb + r) * N + col] = acc[mf][nf][r] + bv;
      }
    }
  } else {
    for (int nf = 0; nf < 4; nf++) {
      int col = n0 + wn + nf * 16 + c0;
      int sec = col >> 10;          // 0=q 1=k 2=v
      int hc = col & 1023;
      int h = hc >> 6, d = hc & 63;
      float bv = bias[col];
      int pcol = n0 + wn + (nf ^ 2) * 16 + c0;  // RoPE partner col (d +/- 32), same lane
      float pbv = bias[pcol];
      for (int mf = 0; mf < 4; mf++) {
        int rowb = m0 + wm + mf * 16 + g * 4;
        for (int r = 0; r < 4; r++) {
          int row = rowb + r;
          int bb = row >> 11, l = row & 2047;
          int bh = bb * 16 + h;
          float v = acc[mf][nf][r] + bv;
          if (sec == 2) {
            Vt[((size_t)bh * 64 + d) * 2048 + l] = f2bf(v);  // V stored transposed [bh][d][l]
          } else {
            int dm = d & 31;
            float cz = cosT[l * 32 + dm], sz = sinT[l * 32 + dm];
            float pv = acc[mf][nf ^ 2][r] + pbv;
            float o = (d < 32) ? (v * cz - pv * sz) : (v * cz + pv * sz);
            u16* dst = (sec == 0) ? Qb : Kb;
            dst[((size_t)bh * 2048 + l) * 64 + d] = f2bf(o);
          }
        }
      }
    }
  }
}

// ---------------- flash attention (swapped-operand, balanced pairs) ----------------
// 512 blocks = 64 bh x 8 q-tile-pairs; block handles q-tiles (pi) and (15-pi): exactly
// 34 KV-tiles of work each -> perfectly balanced, all blocks co-resident (2/CU).
// 4 waves x 32 q rows. KV tile 64. S^T = mfma(K, Q): lane owns one q-row (q=col=c0);
// softmax is lane-local + 2 shfl_xor; P is *already* the 16x16x16 PV B-fragment
// (k = 4g + r) -> no LDS round-trip, no cross-lane P movement.
// K/V double-buffered in LDS via global_load_lds with XOR-swizzled source.
__global__ __launch_bounds__(256, 2) void attn_fwd(
    const u16* __restrict__ Qb, const u16* __restrict__ Kb, const u16* __restrict__ Vt,
    u16* __restrict__ attnOut) {
  __shared__ __attribute__((aligned(16))) u16 kT[2][64 * 64];
  __shared__ __attribute__((aligned(16))) u16 vT[2][64 * 64];
  const int tid = threadIdx.x, lane = tid & 63, wid = tid >> 6;
  // XCD swizzle: 8 blocks sharing one bh land on one XCD (K/V 4MB/XCD = L2-fit)
  const int pblk = blockIdx.x;                 // nwg = 512
  const int lblk = ((pblk & 7) << 6) | (pblk >> 3);
  const int bh = lblk >> 3, pi = lblk & 7;
  const int bb = bh >> 4, h = bh & 15;
  const u16* Qp = Qb + (size_t)bh * 2048 * 64;
  const u16* Kp = Kb + (size_t)bh * 2048 * 64;
  const u16* Vp = Vt + (size_t)bh * 64 * 2048;   // [64 d][2048 l]
  const int g = lane >> 4, c0 = lane & 15;
  const float sc = 0.125f * 1.4426950408889634f;  // scale * log2(e)

  auto stage = [&](int kt, int buf) {
    int kv0 = kt * 64;
    for (int i = 0; i < 2; i++) {
      int chunk = i * 4 + wid;
      int p = chunk * 1024 + lane * 16;
      int row = p >> 7, pb = p & 127;
      int lb = pb ^ ((row & 7) << 4);
      async_copy16((const char*)(Kp + (size_t)(kv0 + row) * 64) + lb,
                   (char*)kT[buf] + chunk * 1024);
      async_copy16((const char*)(Vp + (size_t)row * 2048 + kv0) + lb,
                   (char*)vT[buf] + chunk * 1024);
    }
  };

  for (int seg = 0; seg < 2; ++seg) {
    const int qt = seg ? (15 - pi) : pi;
    const int q0 = qt << 7;
    const int qw = q0 + wid * 32;

    // Q B-fragments hoisted (n = q = c0, k = d contiguous)
    bf8 qfr[2][2];
    for (int qf = 0; qf < 2; qf++)
      for (int ks = 0; ks < 2; ks++)
        qfr[qf][ks] = *(const bf8*)((const char*)Qp +
                                    (size_t)(qw + qf * 16 + c0) * 128 + ks * 64 + g * 16);

    f4 accO[2][4];
    for (int i = 0; i < 2; i++)
      for (int j = 0; j < 4; j++) accO[i][j] = (f4)0.0f;
    float mrun[2] = {-INFINITY, -INFINITY}, lrun[2] = {0.f, 0.f};

    const int nkt = (q0 >> 6) + 2;
    stage(0, 0);
    __syncthreads();

    for (int kt = 0; kt < nkt; ++kt) {
      const int cur = kt & 1;
      if (kt + 1 < nkt) stage(kt + 1, cur ^ 1);
      const char* kbuf = (const char*)kT[cur];
      const char* vbuf = (const char*)vT[cur];
      const int kv0 = kt * 64;

      // S^T = K Q^T  (m = kv, n = q)
      f4 s[2][4];
      for (int i = 0; i < 2; i++)
        for (int j = 0; j < 4; j++) s[i][j] = (f4)0.0f;
      bf8 kf[4][2];
      for (int ks = 0; ks < 2; ks++) {
        int cb = ks * 64 + g * 16;
        for (int kvf = 0; kvf < 4; kvf++) {
          int row = kvf * 16 + c0;
          kf[kvf][ks] = *(const bf8*)(kbuf + (row << 7) + (cb ^ ((row & 7) << 4)));
        }
      }
      for (int ks = 0; ks < 2; ks++)
        for (int kvf = 0; kvf < 4; kvf++)
          for (int qf = 0; qf < 2; qf++)
            s[qf][kvf] = mfma16(kf[kvf][ks], qfr[qf][ks], s[qf][kvf]);

      // scale to log2 domain + causal mask (q = qw+qf*16+c0, kv = kv0+kvf*16+4g+r)
      for (int qf = 0; qf < 2; qf++) {
        int q = qw + qf * 16 + c0;
        for (int kvf = 0; kvf < 4; kvf++)
          for (int r = 0; r < 4; r++) {
            int kv = kv0 + kvf * 16 + 4 * g + r;
            float v = s[qf][kvf][r] * sc;
            s[qf][kvf][r] = (kv > q) ? -INFINITY : v;
          }
      }

      // online softmax: lane-local reduce + 2 shfl_xor across the 4 g-groups
      bf4 pfrag[2][4];
      float pc[2];
      for (int qf = 0; qf < 2; qf++) {
        float mx = s[qf][0][0];
        for (int kvf = 0; kvf < 4; kvf++)
          for (int r = 0; r < 4; r++) mx = fmaxf(mx, s[qf][kvf][r]);
        mx = fmaxf(mx, __shfl_xor(mx, 16));
        mx = fmaxf(mx, __shfl_xor(mx, 32));
        float mn = fmaxf(mrun[qf], mx);
        pc[qf] = fexp2(mrun[qf] - mn);
        float ls = 0.f;
        for (int kvf = 0; kvf < 4; kvf++) {
          bf4 pf;
          for (int r = 0; r < 4; r++) {
            float pv = fexp2(s[qf][kvf][r] - mn);
            ls += pv;
            pf[r] = (short)f2bf(pv);
          }
          pfrag[qf][kvf] = pf;
        }
        ls += __shfl_xor(ls, 16);
        ls += __shfl_xor(ls, 32);
        lrun[qf] = lrun[qf] * pc[qf] + ls;
        mrun[qf] = mn;
      }

      // rescale O
      for (int qf = 0; qf < 2; qf++)
        for (int df = 0; df < 4; df++)
          for (int r = 0; r < 4; r++) accO[qf][df][r] *= pc[qf];

      // O^T += V^T P^T  via 16x16x16 (A = V^T rows d, B = P fragment direct from regs)
      for (int kvf = 0; kvf < 4; kvf++) {
        bf4 vf[4];
        int cb = kvf * 32 + g * 8;
        for (int df = 0; df < 4; df++) {
          int row = df * 16 + c0;
          vf[df] = *(const bf4*)(vbuf + (row << 7) + (cb ^ ((row & 7) << 4)));
        }
        for (int df = 0; df < 4; df++)
          for (int qf = 0; qf < 2; qf++)
            accO[qf][df] = mfma16x16(vf[df], pfrag[qf][kvf], accO[qf][df]);
      }
      __syncthreads();
    }

    // write out: O^T regs -> attnOut [B*L][1024]; d = df*16+4g+r contiguous -> 8B stores
    for (int qf = 0; qf < 2; qf++) {
      float inv = 1.0f / lrun[qf];
      int q = qw + qf * 16 + c0;
      for (int df = 0; df < 4; df++) {
        ushort4 o;
        o.x = f2bf(accO[qf][df][0] * inv);
        o.y = f2bf(accO[qf][df][1] * inv);
        o.z = f2bf(accO[qf][df][2] * inv);
        o.w = f2bf(accO[qf][df][3] * inv);
        int d = df * 16 + 4 * g;
        *(ushort4*)&attnOut[(size_t)(bb * 2048 + q) * 1024 + h * 64 + d] = o;
      }
    }
  }
}

// ---------------- launch ----------------

extern "C" void kernel_launch(void* const* d_in, const int* in_sizes, int n_in,
                              void* d_out, int out_size, void* d_ws, size_t ws_size,
                              hipStream_t stream) {
  const float* x      = (const float*)d_in[0];
  const float* qkv_w  = (const float*)d_in[1];
  const float* qkv_b  = (const float*)d_in[2];
  const float* proj_w = (const float*)d_in[3];
  const float* proj_b = (const float*)d_in[4];
  float* out = (float*)d_out;

  char* ws = (char*)d_ws;
  u16* xb      = (u16*)ws;  ws += (size_t)8192 * 1024 * 2;
  u16* wqkvT   = (u16*)ws;  ws += (size_t)3072 * 1024 * 2;
  u16* wprojT  = (u16*)ws;  ws += (size_t)1024 * 1024 * 2;
  float* cosT  = (float*)ws; ws += (size_t)2048 * 32 * 4;
  float* sinT  = (float*)ws; ws += (size_t)2048 * 32 * 4;
  u16* Qb      = (u16*)ws;  ws += (size_t)64 * 2048 * 64 * 2;
  u16* Kb      = (u16*)ws;  ws += (size_t)64 * 2048 * 64 * 2;
  u16* Vt      = (u16*)ws;  ws += (size_t)64 * 2048 * 64 * 2;
  u16* attnOut = (u16*)ws;  ws += (size_t)8192 * 1024 * 2;
  // total ws usage ~92.3 MB

  convert_bf16_k<<<8192, 256, 0, stream>>>(x, xb, 8192 * 1024 / 4);
  {
    dim3 tg(16, 48);
    transpose_bf16_k<<<tg, 256, 0, stream>>>(qkv_w, wqkvT, 1024, 3072);
  }
  {
    dim3 tg(16, 16);
    transpose_bf16_k<<<tg, 256, 0, stream>>>(proj_w, wprojT, 1024, 1024);
  }
  rope_tables_k<<<256, 256, 0, stream>>>(cosT, sinT);

  gemm_bt<1><<<64 * 24, 256, 0, stream>>>(xb, wqkvT, qkv_b, nullptr,
                                          Qb, Kb, Vt, cosT, sinT, 8192, 3072, 1024);
  attn_fwd<<<512, 256, 0, stream>>>(Qb, Kb, Vt, attnOut);
  gemm_bt<0><<<64 * 8, 256, 0, stream>>>(attnOut, wprojT, proj_b, out,
                                         nullptr, nullptr, nullptr, nullptr, nullptr,
                                         8192, 1024, 1024);
}